// Round 10
// baseline (411.093 us; speedup 1.0000x reference)
//
#include <hip/hip_runtime.h>

#define B_ 128
#define T_ 2048
#define K_ 64
#define C_ 16          // chunks per batch
#define S_ 128         // steps per chunk
#define NSCAN (B_*C_)  // 2048 scan waves
#define NF_ 256
#define L2E 1.44269504088896340736f
#define LN2 0.69314718055994530942f

// ws layout (float offsets). Matrices stored packed bf16 (u32 = 2 rows), 2048 u32/chunk.
#define LOFF (NSCAN*2048)
#define GOFF (LOFF + NSCAN)
#define LLOFF (GOFF + B_)
#define FOFF (LLOFF + B_)

typedef __attribute__((ext_vector_type(2))) unsigned int uint2v;
typedef __attribute__((ext_vector_type(4))) unsigned int uint4v;
typedef __attribute__((ext_vector_type(8))) short short8v;
typedef __attribute__((ext_vector_type(16))) float f32x16;
typedef __attribute__((ext_vector_type(4))) float float4v;

__device__ __forceinline__ float rfl_f(float x) {
    return __int_as_float(__builtin_amdgcn_readfirstlane(__float_as_int(x)));
}
__device__ __forceinline__ unsigned pkbf16(float lo, float hi) {
    unsigned r;
    asm volatile("v_cvt_pk_bf16_f32 %0, %1, %2" : "=v"(r) : "v"(lo), "v"(hi));
    return r;
}
// After: x' = {x.lo_half, y.lo_half}, y' = {x.hi_half, y.hi_half} (halves = lanes<32 / >=32)
__device__ __forceinline__ void swap32(unsigned &x, unsigned &y) {
    uint2v r = __builtin_amdgcn_permlane32_swap(x, y, false, false);
    x = r[0]; y = r[1];
}
__device__ __forceinline__ short8v mk8(unsigned a, unsigned b, unsigned c, unsigned d) {
    uint4v u; u[0] = a; u[1] = b; u[2] = c; u[3] = d;
    return __builtin_bit_cast(short8v, u);
}

// Kernel A: blocks [0,2048) chunk scans; [2048,2176) gold scores; [2176,2432) focal.
__global__ __launch_bounds__(64, 2) void fcrf_scan(
    const float* __restrict__ em, const int* __restrict__ lab,
    const int* __restrict__ msk, const float* __restrict__ trans,
    const float* __restrict__ stv, const float* __restrict__ env,
    float* __restrict__ ws)
{
    const int lane = threadIdx.x;
    const int blk = blockIdx.x;
    const int h = lane >> 5;
    const int cc = lane & 31;

    if (blk < NSCAN) {
        // ---------- chunk transfer-matrix scan ----------
        const int w = blk, b = w >> 4, c = w & 15;
        const float* emB = em + (size_t)b * T_ * K_;
        const int* labB = lab + (size_t)b * T_;
        const int* mskB = msk + (size_t)b * T_;

        // A-frags (constant): A[row=32I+cc][k=16s+8h+j] = exp(trans[k][row])
        short8v as8[2][4];
        #pragma unroll
        for (int I = 0; I < 2; ++I)
            #pragma unroll
            for (int s = 0; s < 4; ++s) {
                float wv[8];
                #pragma unroll
                for (int j = 0; j < 8; ++j)
                    wv[j] = __builtin_amdgcn_exp2f(
                        trans[(16*s + 8*h + j) * K_ + 32*I + cc] * L2E);
                as8[I][s] = mk8(pkbf16(wv[0], wv[1]), pkbf16(wv[2], wv[3]),
                                pkbf16(wv[4], wv[5]), pkbf16(wv[6], wv[7]));
            }

        // B-state = identity. word p of bu4[s][J]: rows k0=16s+8h+2p,k0+1; col=32J+cc
        uint4v bu4[4][2];
        #pragma unroll
        for (int s = 0; s < 4; ++s)
            #pragma unroll
            for (int J = 0; J < 2; ++J)
                #pragma unroll
                for (int p = 0; p < 4; ++p) {
                    int k0 = 16*s + 8*h + 2*p, col = 32*J + cc;
                    unsigned u = 0;
                    if (k0 == col) u |= 0x3F80u;
                    if (k0 + 1 == col) u |= 0x3F800000u;
                    bu4[s][J][p] = u;
                }

        f32x16 ZR;
        #pragma unroll
        for (int i = 0; i < 16; ++i) ZR[i] = 0.f;

        float L = 0.f;
        int t = 1 + c * S_;
        float4v er[2][4];
        int lc, mc2;
        {
            const float4v* ep = (const float4v*)(emB + (size_t)t * K_);
            #pragma unroll
            for (int I = 0; I < 2; ++I)
                #pragma unroll
                for (int Q = 0; Q < 4; ++Q) er[I][Q] = ep[8*I + 2*Q + h];
            lc = labB[t]; mc2 = mskB[t];
        }

        for (int st = 0; st < S_; ++st) {
            // prefetch next step
            int tn = t + 1;
            int tln = tn < T_ ? tn : T_ - 1;
            float4v en[2][4];
            const float4v* epn = (const float4v*)(emB + (size_t)tln * K_);
            #pragma unroll
            for (int I = 0; I < 2; ++I)
                #pragma unroll
                for (int Q = 0; Q < 4; ++Q) en[I][Q] = epn[8*I + 2*Q + h];
            int ln_ = labB[tln], mn_ = mskB[tln];

            bool m = (t < T_) && (lc != -100) && (mc2 != 0);
            if (m) {
                short8v b00 = __builtin_bit_cast(short8v, bu4[0][0]);
                short8v b10 = __builtin_bit_cast(short8v, bu4[1][0]);
                short8v b20 = __builtin_bit_cast(short8v, bu4[2][0]);
                short8v b30 = __builtin_bit_cast(short8v, bu4[3][0]);
                short8v b01 = __builtin_bit_cast(short8v, bu4[0][1]);
                short8v b11 = __builtin_bit_cast(short8v, bu4[1][1]);
                short8v b21 = __builtin_bit_cast(short8v, bu4[2][1]);
                short8v b31 = __builtin_bit_cast(short8v, bu4[3][1]);

                // first quadrant early -> normalizer off its first element
                f32x16 a00 = __builtin_amdgcn_mfma_f32_32x32x16_bf16(as8[0][0], b00, ZR, 0, 0, 0);
                a00 = __builtin_amdgcn_mfma_f32_32x32x16_bf16(as8[0][1], b10, a00, 0, 0, 0);
                a00 = __builtin_amdgcn_mfma_f32_32x32x16_bf16(as8[0][2], b20, a00, 0, 0, 0);
                a00 = __builtin_amdgcn_mfma_f32_32x32x16_bf16(as8[0][3], b30, a00, 0, 0, 0);
                float c00 = rfl_f(a00[0]);
                float lg = __builtin_amdgcn_logf(c00);   // log2(c00)
                L = fmaf(lg, LN2, L);
                float nlg = -lg;
                // row factors: exp(em)/c00 fused into one exp2(fma(..))
                float fr[2][4][4];
                #pragma unroll
                for (int I = 0; I < 2; ++I)
                    #pragma unroll
                    for (int Q = 0; Q < 4; ++Q)
                        #pragma unroll
                        for (int e = 0; e < 4; ++e)
                            fr[I][Q][e] = __builtin_amdgcn_exp2f(
                                fmaf(er[I][Q][e], L2E, nlg));

                f32x16 a01 = __builtin_amdgcn_mfma_f32_32x32x16_bf16(as8[0][0], b01, ZR, 0, 0, 0);
                a01 = __builtin_amdgcn_mfma_f32_32x32x16_bf16(as8[0][1], b11, a01, 0, 0, 0);
                a01 = __builtin_amdgcn_mfma_f32_32x32x16_bf16(as8[0][2], b21, a01, 0, 0, 0);
                a01 = __builtin_amdgcn_mfma_f32_32x32x16_bf16(as8[0][3], b31, a01, 0, 0, 0);
                f32x16 a10 = __builtin_amdgcn_mfma_f32_32x32x16_bf16(as8[1][0], b00, ZR, 0, 0, 0);
                a10 = __builtin_amdgcn_mfma_f32_32x32x16_bf16(as8[1][1], b10, a10, 0, 0, 0);
                a10 = __builtin_amdgcn_mfma_f32_32x32x16_bf16(as8[1][2], b20, a10, 0, 0, 0);
                a10 = __builtin_amdgcn_mfma_f32_32x32x16_bf16(as8[1][3], b30, a10, 0, 0, 0);
                f32x16 a11 = __builtin_amdgcn_mfma_f32_32x32x16_bf16(as8[1][0], b01, ZR, 0, 0, 0);
                a11 = __builtin_amdgcn_mfma_f32_32x32x16_bf16(as8[1][1], b11, a11, 0, 0, 0);
                a11 = __builtin_amdgcn_mfma_f32_32x32x16_bf16(as8[1][2], b21, a11, 0, 0, 0);
                a11 = __builtin_amdgcn_mfma_f32_32x32x16_bf16(as8[1][3], b31, a11, 0, 0, 0);

                // scale by row factors, pack to bf16, half-exchange, write B-state
                #define PACKQ(I, J, ACC)                                              \
                    {                                                                  \
                        _Pragma("unroll")                                              \
                        for (int sg = 0; sg < 2; ++sg) {                               \
                            const int r0 = 8 * sg, s2 = 2 * (I) + sg;                  \
                            unsigned X  = pkbf16((ACC)[r0+0]*fr[I][2*sg][0],           \
                                                 (ACC)[r0+1]*fr[I][2*sg][1]);          \
                            unsigned X2 = pkbf16((ACC)[r0+2]*fr[I][2*sg][2],           \
                                                 (ACC)[r0+3]*fr[I][2*sg][3]);          \
                            unsigned Y  = pkbf16((ACC)[r0+4]*fr[I][2*sg+1][0],         \
                                                 (ACC)[r0+5]*fr[I][2*sg+1][1]);        \
                            unsigned Y2 = pkbf16((ACC)[r0+6]*fr[I][2*sg+1][2],         \
                                                 (ACC)[r0+7]*fr[I][2*sg+1][3]);        \
                            swap32(X, Y);                                              \
                            swap32(X2, Y2);                                            \
                            bu4[s2][J][0] = X;  bu4[s2][J][1] = X2;                    \
                            bu4[s2][J][2] = Y;  bu4[s2][J][3] = Y2;                    \
                        }                                                              \
                    }
                PACKQ(0, 0, a00)
                PACKQ(0, 1, a01)
                PACKQ(1, 0, a10)
                PACKQ(1, 1, a11)
                #undef PACKQ
            }
            #pragma unroll
            for (int I = 0; I < 2; ++I)
                #pragma unroll
                for (int Q = 0; Q < 4; ++Q) er[I][Q] = en[I][Q];
            lc = ln_; mc2 = mn_;
            ++t;
        }

        // store packed G_c: u32 at [(k>>1)*64 + col]  (k0=16s+8h+2p even)
        unsigned* pw = (unsigned*)ws + (size_t)w * 2048;
        #pragma unroll
        for (int s = 0; s < 4; ++s)
            #pragma unroll
            for (int J = 0; J < 2; ++J)
                #pragma unroll
                for (int p = 0; p < 4; ++p)
                    pw[(8*s + 4*h + p) * 64 + 32*J + cc] = bu4[s][J][p];
        if (lane == 0) ws[LOFF + w] = L;
    } else if (blk < NSCAN + B_) {
        // ---------- gold-path score (trans via L2, no LDS) ----------
        const int b = blk - NSCAN;
        const int* labB = lab + (size_t)b * T_;
        const int* mskB = msk + (size_t)b * T_;
        float sacc = 0.f;
        int carry = 0;
        for (int it = 0; it < T_ / 64; ++it) {
            int tt = it * 64 + lane;
            int lb = labB[tt], mk = mskB[tt];
            int tg = (lb == -100) ? 0 : lb;
            int vm = (lb != -100) && (mk != 0);
            unsigned long long bal = __ballot(vm || tt == 0);
            if (bal == ~0ull) {
                int prev = __shfl_up(tg, 1, 64);
                if (lane == 0) prev = carry;
                float term;
                if (tt == 0)
                    term = stv[tg] + em[(size_t)b * T_ * K_ + tg];
                else
                    term = vm ? (trans[prev * K_ + tg] + em[((size_t)b * T_ + tt) * K_ + tg]) : 0.f;
                sacc += term;
                carry = __builtin_amdgcn_readlane(tg, 63);
            } else {
                int cl = carry;
                float sl = 0.f;
                if (lane == 0) {
                    for (int u = 0; u < 64; ++u) {
                        int t2 = it * 64 + u;
                        int lb2 = labB[t2], mk2 = mskB[t2];
                        int tg2 = (lb2 == -100) ? 0 : lb2;
                        int vm2 = (lb2 != -100) && (mk2 != 0);
                        if (t2 == 0) { sl += stv[tg2] + em[(size_t)b * T_ * K_ + tg2]; cl = tg2; }
                        else if (vm2) { sl += trans[cl * K_ + tg2] + em[((size_t)b * T_ + t2) * K_ + tg2]; cl = tg2; }
                    }
                }
                sacc += sl;
                carry = __builtin_amdgcn_readlane(cl, 0);
            }
        }
        if (lane == 0) sacc += env[carry];
        #pragma unroll
        for (int off = 1; off < 64; off <<= 1) sacc += __shfl_xor(sacc, off, 64);
        if (lane == 0) ws[GOFF + b] = sacc;
    } else {
        // ---------- focal-scale partials ----------
        const int fb = blk - NSCAN - B_;
        const float4* em4 = (const float4*)em;
        const int sub = lane >> 4;
        const int cg = lane & 15;
        float facc = 0.f, cacc = 0.f;
        const int base = fb * (B_ * T_ / NF_);
        for (int it = 0; it < (B_ * T_ / NF_) / 4; ++it) {
            int row = base + it * 4 + sub;
            float4 v = em4[row * (K_ / 4) + cg];
            int lb = lab[row];
            int vm = (lb != -100) & (msk[row] != 0);
            int tg = (lb == -100) ? 0 : lb;
            float mx = fmaxf(fmaxf(v.x, v.y), fmaxf(v.z, v.w));
            #pragma unroll
            for (int off = 1; off < 16; off <<= 1) mx = fmaxf(mx, __shfl_xor(mx, off, 64));
            float se = __builtin_amdgcn_exp2f((v.x - mx) * L2E)
                     + __builtin_amdgcn_exp2f((v.y - mx) * L2E)
                     + __builtin_amdgcn_exp2f((v.z - mx) * L2E)
                     + __builtin_amdgcn_exp2f((v.w - mx) * L2E);
            int c0 = cg * 4;
            float sel = ((c0 + 0 == tg) ? v.x : 0.f) + ((c0 + 1 == tg) ? v.y : 0.f)
                      + ((c0 + 2 == tg) ? v.z : 0.f) + ((c0 + 3 == tg) ? v.w : 0.f);
            #pragma unroll
            for (int off = 1; off < 16; off <<= 1) {
                se += __shfl_xor(se, off, 64);
                sel += __shfl_xor(sel, off, 64);
            }
            float p = __builtin_amdgcn_exp2f((sel - mx) * L2E) / se;
            float fw = (1.f - p) * (1.f - p);
            if (cg == 0) {
                facc += vm ? fw : 0.f;
                cacc += vm ? 1.f : 0.f;
            }
        }
        #pragma unroll
        for (int off = 1; off < 64; off <<= 1) {
            facc += __shfl_xor(facc, off, 64);
            cacc += __shfl_xor(cacc, off, 64);
        }
        if (lane == 0) {
            ws[FOFF + 2 * fb] = facc;
            ws[FOFF + 2 * fb + 1] = cacc;
        }
    }
}

// Kernel B: per-batch combine (unpack packed-bf16 chunk matrices)
__global__ __launch_bounds__(64) void fcrf_combine(
    const float* __restrict__ em, const float* __restrict__ stv,
    const float* __restrict__ env, float* __restrict__ ws)
{
    __shared__ float vb[64];
    const int b = blockIdx.x, j = threadIdx.x;
    const int rp = j >> 1;
    const bool hi = (j & 1) != 0;
    float a = stv[j] + em[(size_t)b * T_ * K_ + j];
    float a0 = rfl_f(a);
    float Lv = a0;
    float v = __builtin_amdgcn_exp2f((a - a0) * L2E);
    for (int c = 0; c < C_; ++c) {
        vb[j] = v;
        __syncthreads();
        const uint4v* gp = (const uint4v*)((const unsigned*)ws
                             + (size_t)(b * C_ + c) * 2048 + rp * 64);
        float s0 = 0.f, s1 = 0.f, s2 = 0.f, s3 = 0.f;
        #pragma unroll
        for (int q = 0; q < 16; ++q) {
            uint4v g = gp[q];
            unsigned u0 = g[0], u1 = g[1], u2 = g[2], u3 = g[3];
            float g0 = __uint_as_float(hi ? (u0 & 0xFFFF0000u) : (u0 << 16));
            float g1 = __uint_as_float(hi ? (u1 & 0xFFFF0000u) : (u1 << 16));
            float g2 = __uint_as_float(hi ? (u2 & 0xFFFF0000u) : (u2 << 16));
            float g3 = __uint_as_float(hi ? (u3 & 0xFFFF0000u) : (u3 << 16));
            s0 = fmaf(g0, vb[4*q + 0], s0);
            s1 = fmaf(g1, vb[4*q + 1], s1);
            s2 = fmaf(g2, vb[4*q + 2], s2);
            s3 = fmaf(g3, vb[4*q + 3], s3);
        }
        float out = (s0 + s1) + (s2 + s3);
        float o0 = rfl_f(out);
        v = out * __builtin_amdgcn_rcpf(o0);
        Lv = fmaf(__builtin_amdgcn_logf(o0), LN2, Lv) + ws[LOFF + b * C_ + c];
        __syncthreads();
    }
    float x = v * __builtin_amdgcn_exp2f(env[j] * L2E);
    #pragma unroll
    for (int off = 1; off < 64; off <<= 1) x += __shfl_xor(x, off, 64);
    float logZ = fmaf(__builtin_amdgcn_logf(x), LN2, Lv);
    if (j == 0) ws[LLOFF + b] = ws[GOFF + b] - logZ;
}

__global__ __launch_bounds__(64) void fcrf_final(const float* __restrict__ ws,
                                                 float* __restrict__ out)
{
    const int lane = threadIdx.x;
    float llh = ws[LLOFF + lane] + ws[LLOFF + 64 + lane];
    float f = 0.f, c = 0.f;
    #pragma unroll
    for (int k = 0; k < NF_ / 64; ++k) {
        int i = lane + 64 * k;
        f += ws[FOFF + 2 * i];
        c += ws[FOFF + 2 * i + 1];
    }
    #pragma unroll
    for (int off = 1; off < 64; off <<= 1) {
        llh += __shfl_xor(llh, off, 64);
        f += __shfl_xor(f, off, 64);
        c += __shfl_xor(c, off, 64);
    }
    if (lane == 0) {
        float crf = -(llh * (1.0f / B_));
        float scale = f / fmaxf(c, 1.f);
        scale = fmaxf(scale, 0.1f);
        out[0] = crf * scale;
    }
}

extern "C" void kernel_launch(void* const* d_in, const int* in_sizes, int n_in,
                              void* d_out, int out_size, void* d_ws, size_t ws_size,
                              hipStream_t stream) {
    const float* em = (const float*)d_in[0];
    const int* lab = (const int*)d_in[1];
    const int* msk = (const int*)d_in[2];  // jnp bool stored as int32
    const float* trans = (const float*)d_in[3];
    const float* stv = (const float*)d_in[4];
    const float* env = (const float*)d_in[5];
    float* ws = (float*)d_ws;
    float* out = (float*)d_out;

    fcrf_scan<<<dim3(NSCAN + B_ + NF_), dim3(64), 0, stream>>>(em, lab, msk, trans, stv, env, ws);
    fcrf_combine<<<dim3(B_), dim3(64), 0, stream>>>(em, stv, env, ws);
    fcrf_final<<<dim3(1), dim3(64), 0, stream>>>(ws, out);
}